// Round 7
// baseline (51.135 us; speedup 1.0000x reference)
//
#include <hip/hip_runtime.h>
#include <hip/hip_bf16.h>
#include <math.h>

// Problem: N=32768, M=8192, Z=64.  loss = mean_m min_n ||tanh(z_n) - e_m||^2
#define NN 32768
#define MM 8192
#define ZD 64
#define WAVES 4
#define MW 64                  // m-cols per wave (2 x 32-col MFMA tiles)
#define MBLK (WAVES * MW)      // 256 m-cols per block
#define NMB (MM / MBLK)        // 32 m-blocks
#define NCHUNKS 32             // split of N across chunks
#define CHUNK (NN / NCHUNKS)   // 1024
#define NROWS 128              // n-rows staged per iteration
#define NITER (CHUNK / NROWS)  // 8
#define SCALE 4294967296.0     // 2^32 fixed-point for deterministic sum

typedef __attribute__((ext_vector_type(8))) short bf16x8;   // 8 bf16 = 4 VGPR
typedef __attribute__((ext_vector_type(4))) float f32x4;
typedef __attribute__((ext_vector_type(16))) float f32x16;

__device__ inline unsigned short f2bf(float f) {  // RNE f32 -> bf16 (finite)
  unsigned u = __float_as_uint(f);
  return (unsigned short)((u + 0x7fffu + ((u >> 16) & 1u)) >> 16);
}
__device__ inline float bf2f(unsigned short h) {
  return __uint_as_float(((unsigned)h) << 16);
}

// ---------------------------------------------------------------------------
// prep (fused): blocks [0, NN/32) do z-rows; blocks [NN/32, ..) do e-rows and
// re-init dmin/acc/cnt (graph replays leave them dirty).
//   z: zb[n][k] = bf16(tanh(z[n][k])), zn[n] = sum(quantized^2)
//   e: q = bf16(e); eb[m][k] = bf16(-2*q) (exact); en[m] = sum q^2
// ---------------------------------------------------------------------------
__global__ __launch_bounds__(256) void prep(
    const float* __restrict__ z, const float* __restrict__ e,
    unsigned short* __restrict__ zb, float* __restrict__ zn,
    unsigned short* __restrict__ eb, float* __restrict__ en,
    unsigned* __restrict__ dmin, unsigned long long* __restrict__ acc,
    unsigned* __restrict__ cnt) {
  const int q = threadIdx.x & 7;  // 8 f32 each
  if (blockIdx.x < NN / 32) {
    const int row = blockIdx.x * 32 + (threadIdx.x >> 3);
    const size_t base = (size_t)row * ZD + q * 8;
    float4 v0 = *reinterpret_cast<const float4*>(&z[base]);
    float4 v1 = *reinterpret_cast<const float4*>(&z[base + 4]);
    float in[8] = {v0.x, v0.y, v0.z, v0.w, v1.x, v1.y, v1.z, v1.w};
    unsigned short b[8];
    float s = 0.f;
#pragma unroll
    for (int i = 0; i < 8; ++i) {
      b[i] = f2bf(tanhf(in[i]));
      float r = bf2f(b[i]);
      s += r * r;
    }
    *reinterpret_cast<bf16x8*>(&zb[base]) = *reinterpret_cast<bf16x8*>(b);
    s += __shfl_xor(s, 1, 64);
    s += __shfl_xor(s, 2, 64);
    s += __shfl_xor(s, 4, 64);
    if (q == 0) zn[row] = s;
  } else {
    const int row = (blockIdx.x - NN / 32) * 32 + (threadIdx.x >> 3);
    const size_t base = (size_t)row * ZD + q * 8;
    float4 v0 = *reinterpret_cast<const float4*>(&e[base]);
    float4 v1 = *reinterpret_cast<const float4*>(&e[base + 4]);
    float in[8] = {v0.x, v0.y, v0.z, v0.w, v1.x, v1.y, v1.z, v1.w};
    unsigned short b[8];
    float s = 0.f;
#pragma unroll
    for (int i = 0; i < 8; ++i) {
      unsigned short qb = f2bf(in[i]);
      float r = bf2f(qb);
      s += r * r;
      b[i] = f2bf(-2.f * r);  // exact: power-of-2 scale + sign
    }
    *reinterpret_cast<bf16x8*>(&eb[base]) = *reinterpret_cast<bf16x8*>(b);
    s += __shfl_xor(s, 1, 64);
    s += __shfl_xor(s, 2, 64);
    s += __shfl_xor(s, 4, 64);
    if (q == 0) {
      en[row] = s;
      dmin[row] = 0xFFFFFFFFu;  // +inf key
    }
    if (blockIdx.x == NN / 32 && threadIdx.x == 0) {
      *acc = 0ULL;
      *cnt = 0u;
    }
  }
}

// ---------------------------------------------------------------------------
// min_dist: dmin[m] <- atomicMin over n of key( zn[n] - 2*z_n.e_m )
// 1024 blocks (4/CU), 4 waves x 64 m-cols (2 x 32-col 32x32x16 MFMA tiles).
// A-tile (128 n-rows) shared via LDS: global_load_lds(16B) double-buffered,
// XOR-swizzled (linear LDS dest + inverse-swizzled global source + swizzled
// ds_read_b128). zn folded into the MFMA C-operand (C/D: col=lane&31,
// row=(reg&3)+8*(reg>>2)+4*(lane>>5)). Ordered-uint atomicMin: deterministic
// (min is order-invariant). XCD-bijective block remap.
// ---------------------------------------------------------------------------
__global__ __launch_bounds__(256, 4) void min_dist(
    const unsigned short* __restrict__ zb, const unsigned short* __restrict__ eb,
    const float* __restrict__ zn, unsigned* __restrict__ dmin) {
  __shared__ __align__(128) unsigned short zlds[2][NROWS * ZD];  // 2 x 16 KB
  // XCD-contiguous remap (grid = 1024, 1024 % 8 == 0 -> bijective):
  const int wg = ((blockIdx.x & 7) << 7) + (blockIdx.x >> 3);
  const int mb = wg & (NMB - 1);   // m-block 0..31
  const int cb = wg >> 5;          // chunk 0..31  (4 consecutive per XCD)
  const int lane = threadIdx.x & 63;
  const int wv = threadIdx.x >> 6;  // 0..3
  const int lc = lane & 31;         // fragment row (A) / col (B,D)
  const int hi = lane >> 5;         // 0..1 k-half
  const int m0 = mb * MBLK + wv * MW;
  const int nb0 = cb * CHUNK;

  // staging: 16 x 1KB pieces/iter (8 rows each), 4 per wave. Lane l writes
  // LDS byte piece*1024 + l*16 (linear dest); source inverse-swizzled so
  // reads can apply slot ^= (row&7). Piece stride 1024B in global AND LDS.
  const int srow = lane >> 3;           // row within piece, 0..7
  const int sslot = (lane & 7) ^ srow;  // inverse-swizzled 16B slot
  const char* zsrc = (const char*)zb + (size_t)nb0 * 128 +
                     (wv * 32 + srow) * 128 + (sslot << 4);
  char* ldst0 = (char*)&zlds[0][0] + wv * 4096;
  char* ldst1 = (char*)&zlds[1][0] + wv * 4096;

  // B fragments: 2 tiles of 32 m-cols, K=64 as 4 sub-K of 16 (32 VGPR)
  // B layout: col = lane&31, k = kk*16 + (lane>>5)*8 + j
  bf16x8 bfr[2][4];
#pragma unroll
  for (int t = 0; t < 2; ++t)
#pragma unroll
    for (int kk = 0; kk < 4; ++kk)
      bfr[t][kk] = *reinterpret_cast<const bf16x8*>(
          &eb[(size_t)(m0 + t * 32 + lc) * ZD + kk * 16 + hi * 8]);

  float minv[2] = {3.4e38f, 3.4e38f};

  auto stage = [&](char* dst, const char* src) {
#pragma unroll
    for (int j = 0; j < 4; ++j)
      __builtin_amdgcn_global_load_lds(
          (const __attribute__((address_space(1))) unsigned int*)(src + j * 1024),
          (__attribute__((address_space(3))) unsigned int*)(dst + j * 1024),
          16, 0, 0);
  };

  const float* znp = zn + nb0;

  stage(ldst0, zsrc);
  zsrc += NROWS * 128;
  __syncthreads();  // vmcnt(0) drain before s_barrier

  for (int it = 0; it < NITER; ++it) {
    const char* lbase = (it & 1) ? (const char*)&zlds[1][0] : (const char*)&zlds[0][0];
    if (it + 1 < NITER) {
      stage((it & 1) ? ldst0 : ldst1, zsrc);
      zsrc += NROWS * 128;
    }
#pragma unroll
    for (int s = 0; s < NROWS / 32; ++s) {
      // A: row = s*32 + (lane&31), 16B at swizzled slot (kk*2+hi)^(row&7)
      const int rb = (s * 32 + lc) * 128;
      bf16x8 a[4];
#pragma unroll
      for (int kk = 0; kk < 4; ++kk)
        a[kk] = *reinterpret_cast<const bf16x8*>(
            lbase + rb + ((((kk << 1) + hi) ^ (lane & 7)) << 4));
      // C-in: zn at rows (q&3)+8*(q>>2)+4*hi
      f32x16 znc;
#pragma unroll
      for (int g = 0; g < 4; ++g) {
        f32x4 L = *reinterpret_cast<const f32x4*>(znp + s * 32 + g * 8 + hi * 4);
        znc[g * 4 + 0] = L[0];
        znc[g * 4 + 1] = L[1];
        znc[g * 4 + 2] = L[2];
        znc[g * 4 + 3] = L[3];
      }
#pragma unroll
      for (int t = 0; t < 2; ++t) {
        f32x16 accv = znc;
#pragma unroll
        for (int kk = 0; kk < 4; ++kk)
          accv = __builtin_amdgcn_mfma_f32_32x32x16_bf16(a[kk], bfr[t][kk], accv, 0, 0, 0);
        // in-lane min3 tree over 16 accs
        float x0 = fminf(fminf(accv[0], accv[1]), accv[2]);
        float x1 = fminf(fminf(accv[3], accv[4]), accv[5]);
        float x2 = fminf(fminf(accv[6], accv[7]), accv[8]);
        float x3 = fminf(fminf(accv[9], accv[10]), accv[11]);
        float x4 = fminf(fminf(accv[12], accv[13]), accv[14]);
        float y0 = fminf(fminf(x0, x1), x2);
        float y1 = fminf(fminf(x3, x4), accv[15]);
        minv[t] = fminf(fminf(y0, y1), minv[t]);
      }
    }
    znp += NROWS;
    __syncthreads();  // next-stage landed; prev buf safe to overwrite
  }

  // cross-lane: rows 4*hi covered -> one xor-32 merge; lanes 0..31 hold col
#pragma unroll
  for (int t = 0; t < 2; ++t) {
    float v = minv[t];
    v = fminf(v, __shfl_xor(v, 32, 64));
    if (lane < 32) {
      unsigned bits = __float_as_uint(v);
      unsigned key = (bits & 0x80000000u) ? ~bits : (bits | 0x80000000u);
      atomicMin(&dmin[m0 + t * 32 + lane], key);  // device-scope, order-inv
    }
  }
}

// ---------------------------------------------------------------------------
// finalize: 32 blocks x 256: sum_m ( en[m] + decode(dmin[m]) ) via
// fixed-point i64 atomic (order-invariant -> deterministic); last block out.
// ---------------------------------------------------------------------------
__global__ __launch_bounds__(256) void finalize(const unsigned* __restrict__ dmin,
                                                const float* __restrict__ en,
                                                unsigned long long* __restrict__ acc,
                                                unsigned* __restrict__ cnt,
                                                float* __restrict__ out) {
  const int m = blockIdx.x * 256 + threadIdx.x;
  unsigned key = dmin[m];
  unsigned bits = (key & 0x80000000u) ? (key & 0x7FFFFFFFu) : ~key;
  float mv = __uint_as_float(bits);
  double s = (double)(mv + en[m]);
  __shared__ double sred[256];
  sred[threadIdx.x] = s;
  __syncthreads();
  for (int off = 128; off > 0; off >>= 1) {
    if ((int)threadIdx.x < off) sred[threadIdx.x] += sred[threadIdx.x + off];
    __syncthreads();
  }
  if (threadIdx.x == 0) {
    unsigned long long iv = (unsigned long long)(sred[0] * SCALE + 0.5);
    atomicAdd(acc, iv);
    __threadfence();
    unsigned d = atomicAdd(cnt, 1u);
    if (d == MM / 256 - 1) {  // last block: all acc-adds happened-before
      __threadfence();
      unsigned long long tot = atomicAdd(acc, 0ULL);
      out[0] = (float)((double)tot / SCALE / (double)MM);
    }
  }
}

extern "C" void kernel_launch(void* const* d_in, const int* in_sizes, int n_in,
                              void* d_out, int out_size, void* d_ws, size_t ws_size,
                              hipStream_t stream) {
  const float* z = (const float*)d_in[0];  // (N, 64) f32
  const float* e = (const float*)d_in[1];  // (M, 64) f32
  float* out = (float*)d_out;

  unsigned short* zb = (unsigned short*)d_ws;          // NN*64 bf16 (4 MB)
  unsigned short* eb = zb + (size_t)NN * ZD;           // MM*64 bf16 (1 MB)
  float* zn = (float*)(eb + (size_t)MM * ZD);          // NN f32
  float* en = zn + NN;                                 // MM f32
  unsigned* dmin = (unsigned*)(en + MM);               // MM u32
  unsigned long long* acc = (unsigned long long*)(dmin + MM);  // 8B
  unsigned* cnt = (unsigned*)(acc + 1);                // 4B

  prep<<<(NN + MM) / 32, 256, 0, stream>>>(z, e, zb, zn, eb, en, dmin, acc, cnt);
  min_dist<<<NMB * NCHUNKS, 256, 0, stream>>>(zb, eb, zn, dmin);
  finalize<<<MM / 256, 256, 0, stream>>>(dmin, en, acc, cnt, out);
}

// Round 8
// 46.596 us; speedup vs baseline: 1.0974x; 1.0974x over previous
//
#include <hip/hip_runtime.h>
#include <hip/hip_bf16.h>
#include <math.h>

// Problem: N=32768, M=8192, Z=64.  loss = mean_m min_n ||tanh(z_n) - e_m||^2
#define NN 32768
#define MM 8192
#define ZD 64
#define WAVES 4
#define MW 64                  // m-cols per wave (4 x 16-col MFMA tiles)
#define MBLK (WAVES * MW)      // 256 m-cols per block
#define NMB (MM / MBLK)        // 32 m-blocks
#define NCHUNKS 32             // split of N across chunks
#define CHUNK (NN / NCHUNKS)   // 1024
#define NROWS 128              // n-rows staged per iteration
#define NITER (CHUNK / NROWS)  // 8
#define SCALE 4294967296.0     // 2^32 fixed-point for deterministic sum

typedef __attribute__((ext_vector_type(8))) short bf16x8;  // 8 bf16 = 4 VGPR
typedef __attribute__((ext_vector_type(4))) float f32x4;

__device__ inline unsigned short f2bf(float f) {  // RNE f32 -> bf16 (finite)
  unsigned u = __float_as_uint(f);
  return (unsigned short)((u + 0x7fffu + ((u >> 16) & 1u)) >> 16);
}
__device__ inline float bf2f(unsigned short h) {
  return __uint_as_float(((unsigned)h) << 16);
}

// ---------------------------------------------------------------------------
// prep (fused): blocks [0, NN/32) do z-rows; blocks [NN/32, ..) do e-rows and
// re-init dmin/acc/cnt (graph replays leave them dirty).
//   z: zb[n][k] = bf16(tanh(z[n][k])), zn[n] = sum(quantized^2)
//   e: q = bf16(e); eb[m][k] = bf16(-2*q) (exact); en[m] = sum q^2
// ---------------------------------------------------------------------------
__global__ __launch_bounds__(256) void prep(
    const float* __restrict__ z, const float* __restrict__ e,
    unsigned short* __restrict__ zb, float* __restrict__ zn,
    unsigned short* __restrict__ eb, float* __restrict__ en,
    unsigned* __restrict__ dmin, unsigned long long* __restrict__ acc,
    unsigned* __restrict__ cnt) {
  const int q = threadIdx.x & 7;  // 8 f32 each
  if (blockIdx.x < NN / 32) {
    const int row = blockIdx.x * 32 + (threadIdx.x >> 3);
    const size_t base = (size_t)row * ZD + q * 8;
    float4 v0 = *reinterpret_cast<const float4*>(&z[base]);
    float4 v1 = *reinterpret_cast<const float4*>(&z[base + 4]);
    float in[8] = {v0.x, v0.y, v0.z, v0.w, v1.x, v1.y, v1.z, v1.w};
    unsigned short b[8];
    float s = 0.f;
#pragma unroll
    for (int i = 0; i < 8; ++i) {
      b[i] = f2bf(tanhf(in[i]));
      float r = bf2f(b[i]);
      s += r * r;
    }
    *reinterpret_cast<bf16x8*>(&zb[base]) = *reinterpret_cast<bf16x8*>(b);
    s += __shfl_xor(s, 1, 64);
    s += __shfl_xor(s, 2, 64);
    s += __shfl_xor(s, 4, 64);
    if (q == 0) zn[row] = s;
  } else {
    const int row = (blockIdx.x - NN / 32) * 32 + (threadIdx.x >> 3);
    const size_t base = (size_t)row * ZD + q * 8;
    float4 v0 = *reinterpret_cast<const float4*>(&e[base]);
    float4 v1 = *reinterpret_cast<const float4*>(&e[base + 4]);
    float in[8] = {v0.x, v0.y, v0.z, v0.w, v1.x, v1.y, v1.z, v1.w};
    unsigned short b[8];
    float s = 0.f;
#pragma unroll
    for (int i = 0; i < 8; ++i) {
      unsigned short qb = f2bf(in[i]);
      float r = bf2f(qb);
      s += r * r;
      b[i] = f2bf(-2.f * r);  // exact: power-of-2 scale + sign
    }
    *reinterpret_cast<bf16x8*>(&eb[base]) = *reinterpret_cast<bf16x8*>(b);
    s += __shfl_xor(s, 1, 64);
    s += __shfl_xor(s, 2, 64);
    s += __shfl_xor(s, 4, 64);
    if (q == 0) {
      en[row] = s;
      dmin[row] = 0xFFFFFFFFu;  // +inf key
    }
    if (blockIdx.x == NN / 32 && threadIdx.x == 0) {
      *acc = 0ULL;
      *cnt = 0u;
    }
  }
}

// ---------------------------------------------------------------------------
// min_dist: dmin[m] <- atomicMin over n of key( zn[n] - 2*z_n.e_m )
// 1024 blocks (4/CU), 4 waves x 64 m-cols (4 x 16-col 16x16x32 MFMA tiles;
// f32x4 accumulators stay in VGPRs — the 32x32 f32x16 variant spilled to
// AGPRs with v_accvgpr move overhead and 4-way LDS read conflicts, R7).
// A-tile (128 n-rows) shared via LDS: global_load_lds(16B) double-buffered,
// XOR-swizzled (linear LDS dest + inverse-swizzled global source + swizzled
// ds_read_b128 -> 0 measured conflicts). zn folded into the MFMA C-operand.
// Ordered-uint atomicMin: deterministic. XCD-bijective block remap.
// ---------------------------------------------------------------------------
__global__ __launch_bounds__(256, 4) void min_dist(
    const unsigned short* __restrict__ zb, const unsigned short* __restrict__ eb,
    const float* __restrict__ zn, unsigned* __restrict__ dmin) {
  __shared__ __align__(128) unsigned short zlds[2][NROWS * ZD];  // 2 x 16 KB
  // XCD-contiguous remap (grid = 1024, 1024 % 8 == 0 -> bijective):
  const int wg = ((blockIdx.x & 7) << 7) + (blockIdx.x >> 3);
  const int mb = wg & (NMB - 1);   // m-block 0..31
  const int cb = wg >> 5;          // chunk 0..31  (4 consecutive per XCD)
  const int lane = threadIdx.x & 63;
  const int wv = threadIdx.x >> 6;   // 0..3
  const int lr = lane & 15;          // fragment row/col
  const int lg = lane >> 4;          // 0..3 k-group
  const int m0 = mb * MBLK + wv * MW;
  const int nb0 = cb * CHUNK;

  // staging: 16 x 1KB pieces/iter (8 rows each), 4 per wave. Lane l writes
  // LDS byte piece*1024 + l*16 (linear dest); source inverse-swizzled so
  // reads can apply slot ^= (row&7). Piece stride 1024B in global AND LDS.
  const int srow = lane >> 3;           // row within piece, 0..7
  const int sslot = (lane & 7) ^ srow;  // inverse-swizzled 16B slot
  const char* zsrc = (const char*)zb + (size_t)nb0 * 128 +
                     (wv * 32 + srow) * 128 + (sslot << 4);
  char* ldst0 = (char*)&zlds[0][0] + wv * 4096;
  char* ldst1 = (char*)&zlds[1][0] + wv * 4096;

  // B fragments: 4 tiles of 16 m-cols, K=64 in two halves (32 VGPR)
  bf16x8 bfr[4][2];
#pragma unroll
  for (int t = 0; t < 4; ++t)
#pragma unroll
    for (int h = 0; h < 2; ++h)
      bfr[t][h] = *reinterpret_cast<const bf16x8*>(
          &eb[(size_t)(m0 + t * 16 + lr) * ZD + h * 32 + lg * 8]);

  float minv[4] = {3.4e38f, 3.4e38f, 3.4e38f, 3.4e38f};

  auto stage = [&](char* dst, const char* src) {
#pragma unroll
    for (int j = 0; j < 4; ++j)
      __builtin_amdgcn_global_load_lds(
          (const __attribute__((address_space(1))) unsigned int*)(src + j * 1024),
          (__attribute__((address_space(3))) unsigned int*)(dst + j * 1024),
          16, 0, 0);
  };

  const float* znp = zn + nb0;
  const int x0 = (lg * 16) ^ ((lr & 7) << 4);  // swizzled 16B slot, K-half 0

  stage(ldst0, zsrc);
  zsrc += NROWS * 128;
  __syncthreads();  // vmcnt(0) drain before s_barrier

  for (int it = 0; it < NITER; ++it) {
    const char* lbase = (it & 1) ? (const char*)&zlds[1][0] : (const char*)&zlds[0][0];
    if (it + 1 < NITER) {
      stage((it & 1) ? ldst0 : ldst1, zsrc);
      zsrc += NROWS * 128;
    }
#pragma unroll
    for (int s = 0; s < NROWS / 16; ++s) {
      const int rb = (s * 16 + lr) * 128;
      bf16x8 a0 = *reinterpret_cast<const bf16x8*>(lbase + rb + x0);
      bf16x8 a1 = *reinterpret_cast<const bf16x8*>(lbase + rb + (x0 ^ 64));
      f32x4 znv = *reinterpret_cast<const f32x4*>(znp + s * 16 + lg * 4);
#pragma unroll
      for (int t = 0; t < 4; ++t) {
        // acc = zn[n] + sum_k z_n[k] * (-2 e_m[k])
        f32x4 acc = __builtin_amdgcn_mfma_f32_16x16x32_bf16(a0, bfr[t][0], znv, 0, 0, 0);
        acc = __builtin_amdgcn_mfma_f32_16x16x32_bf16(a1, bfr[t][1], acc, 0, 0, 0);
        // two v_min3-fusable triples: min(acc[0..3], running)
        float x = fminf(fminf(acc[0], acc[1]), acc[2]);
        minv[t] = fminf(fminf(x, acc[3]), minv[t]);
      }
    }
    znp += NROWS;
    __syncthreads();  // next-stage landed; prev buf safe to overwrite
  }

  // cross-lane: min over the 4 row-groups (lg); lanes 0..15 hold col lr
#pragma unroll
  for (int t = 0; t < 4; ++t) {
    float v = minv[t];
    v = fminf(v, __shfl_xor(v, 16, 64));
    v = fminf(v, __shfl_xor(v, 32, 64));
    if (lg == 0) {
      unsigned bits = __float_as_uint(v);
      unsigned key = (bits & 0x80000000u) ? ~bits : (bits | 0x80000000u);
      atomicMin(&dmin[m0 + t * 16 + lr], key);  // device-scope, order-inv
    }
  }
}

// ---------------------------------------------------------------------------
// finalize: 32 blocks x 256: sum_m ( en[m] + decode(dmin[m]) ) via
// fixed-point i64 atomic (order-invariant -> deterministic); last block out.
// ---------------------------------------------------------------------------
__global__ __launch_bounds__(256) void finalize(const unsigned* __restrict__ dmin,
                                                const float* __restrict__ en,
                                                unsigned long long* __restrict__ acc,
                                                unsigned* __restrict__ cnt,
                                                float* __restrict__ out) {
  const int m = blockIdx.x * 256 + threadIdx.x;
  unsigned key = dmin[m];
  unsigned bits = (key & 0x80000000u) ? (key & 0x7FFFFFFFu) : ~key;
  float mv = __uint_as_float(bits);
  double s = (double)(mv + en[m]);
  __shared__ double sred[256];
  sred[threadIdx.x] = s;
  __syncthreads();
  for (int off = 128; off > 0; off >>= 1) {
    if ((int)threadIdx.x < off) sred[threadIdx.x] += sred[threadIdx.x + off];
    __syncthreads();
  }
  if (threadIdx.x == 0) {
    unsigned long long iv = (unsigned long long)(sred[0] * SCALE + 0.5);
    atomicAdd(acc, iv);
    __threadfence();
    unsigned d = atomicAdd(cnt, 1u);
    if (d == MM / 256 - 1) {  // last block: all acc-adds happened-before
      __threadfence();
      unsigned long long tot = atomicAdd(acc, 0ULL);
      out[0] = (float)((double)tot / SCALE / (double)MM);
    }
  }
}

extern "C" void kernel_launch(void* const* d_in, const int* in_sizes, int n_in,
                              void* d_out, int out_size, void* d_ws, size_t ws_size,
                              hipStream_t stream) {
  const float* z = (const float*)d_in[0];  // (N, 64) f32
  const float* e = (const float*)d_in[1];  // (M, 64) f32
  float* out = (float*)d_out;

  unsigned short* zb = (unsigned short*)d_ws;          // NN*64 bf16 (4 MB)
  unsigned short* eb = zb + (size_t)NN * ZD;           // MM*64 bf16 (1 MB)
  float* zn = (float*)(eb + (size_t)MM * ZD);          // NN f32
  float* en = zn + NN;                                 // MM f32
  unsigned* dmin = (unsigned*)(en + MM);               // MM u32
  unsigned long long* acc = (unsigned long long*)(dmin + MM);  // 8B
  unsigned* cnt = (unsigned*)(acc + 1);                // 4B

  prep<<<(NN + MM) / 32, 256, 0, stream>>>(z, e, zb, zn, eb, en, dmin, acc, cnt);
  min_dist<<<NMB * NCHUNKS, 256, 0, stream>>>(zb, eb, zn, dmin);
  finalize<<<MM / 256, 256, 0, stream>>>(dmin, en, acc, cnt, out);
}